// Round 8
// baseline (317.573 us; speedup 1.0000x reference)
//
#include <hip/hip_runtime.h>

typedef __bf16 bf16_t;
typedef __bf16 bf16x8 __attribute__((ext_vector_type(8)));
typedef float  f32x4  __attribute__((ext_vector_type(4)));

#define MFMA16(a, b, c) __builtin_amdgcn_mfma_f32_16x16x32_bf16((a), (b), (c), 0, 0, 0)

__device__ __forceinline__ void gload_lds16(const void* g, void* l) {
  __builtin_amdgcn_global_load_lds((__attribute__((address_space(1))) void*)(g),
                                   (__attribute__((address_space(3))) void*)(l),
                                   16, 0, 0);
}

// ---------------------------------------------------------------- fused convert (x, wq, wk, wv, wo)
__global__ __launch_bounds__(256) void cvt_all(const float* __restrict__ x,
                                               const float* __restrict__ wq,
                                               const float* __restrict__ wk,
                                               const float* __restrict__ wv,
                                               const float* __restrict__ wo,
                                               bf16_t* __restrict__ xb,
                                               bf16_t* __restrict__ wqkv,
                                               bf16_t* __restrict__ wob) {
  int i = (blockIdx.x * 256 + threadIdx.x) * 8;
  const float* src;
  bf16_t* dst;
  int off;
  if (i < 4194304)      { src = x;  dst = xb;             off = i; }
  else if (i < 5242880) { src = wq; dst = wqkv;           off = i - 4194304; }
  else if (i < 5505024) { src = wk; dst = wqkv + 1048576; off = i - 5242880; }
  else if (i < 5767168) { src = wv; dst = wqkv + 1310720; off = i - 5505024; }
  else                  { src = wo; dst = wob;            off = i - 5767168; }
  const float4* pp = reinterpret_cast<const float4*>(src + off);
  float4 a = pp[0], b = pp[1];
  bf16x8 v;
  v[0] = (bf16_t)a.x; v[1] = (bf16_t)a.y; v[2] = (bf16_t)a.z; v[3] = (bf16_t)a.w;
  v[4] = (bf16_t)b.x; v[5] = (bf16_t)b.y; v[6] = (bf16_t)b.z; v[7] = (bf16_t)b.w;
  *reinterpret_cast<bf16x8*>(dst + off) = v;
}

// ---------------------------------------------------------------- GEMM  C[M,N] = A[M,K] * B[N,K]^T
// Dual-write epilogue when kp/vt non-null: cols [1024,1280) -> kp[4][4096][64]
// PRE-SCALED by 0.125*log2(e) (attn uses exp2 directly); cols [1280,1536) ->
// vt[256][4096] transposed.
template <typename T>
__global__ __launch_bounds__(256) void gemm_bt(const bf16_t* __restrict__ A,
                                               const bf16_t* __restrict__ B,
                                               T* __restrict__ C,
                                               int M, int N, int K,
                                               bf16_t* __restrict__ kp,
                                               bf16_t* __restrict__ vt) {
  constexpr int BK = 64;
  int tid  = threadIdx.x;
  int lane = tid & 63, w = tid >> 6;
  int wr = w >> 1, wc = w & 1;
  int l15 = lane & 15, lhi = lane >> 4;
  int row0 = blockIdx.y * 128, col0 = blockIdx.x * 128;

  __shared__ alignas(16) char smem[128 * BK * 2 * 2];
  char* sA = smem;
  char* sB = smem + 128 * BK * 2;

  f32x4 acc[4][4] = {};

  for (int k0 = 0; k0 < K; k0 += BK) {
#pragma unroll
    for (int i = 0; i < 4; ++i) {
      int c = i * 256 + tid;
      int r = c >> 3, kc = c & 7;
      int kk = k0 + ((kc ^ (r & 7)) << 3);
      gload_lds16(A + (size_t)(row0 + r) * K + kk, sA + c * 16);
      gload_lds16(B + (size_t)(col0 + r) * K + kk, sB + c * 16);
    }
    __syncthreads();
#pragma unroll
    for (int s = 0; s < 2; ++s) {
      bf16x8 af[4], bfr[4];
#pragma unroll
      for (int mi = 0; mi < 4; ++mi) {
        int r = wr * 64 + mi * 16 + l15;
        af[mi] = *reinterpret_cast<const bf16x8*>(
            sA + r * 128 + (((s * 4 + lhi) ^ (r & 7)) << 4));
      }
#pragma unroll
      for (int nj = 0; nj < 4; ++nj) {
        int r = wc * 64 + nj * 16 + l15;
        bfr[nj] = *reinterpret_cast<const bf16x8*>(
            sB + r * 128 + (((s * 4 + lhi) ^ (r & 7)) << 4));
      }
#pragma unroll
      for (int mi = 0; mi < 4; ++mi)
#pragma unroll
        for (int nj = 0; nj < 4; ++nj)
          acc[mi][nj] = MFMA16(af[mi], bfr[nj], acc[mi][nj]);
    }
    __syncthreads();
  }

  const float KSCALE = 0.18033688f;   // 0.125 * log2(e)
#pragma unroll
  for (int mi = 0; mi < 4; ++mi)
#pragma unroll
    for (int nj = 0; nj < 4; ++nj) {
      int colb = col0 + wc * 64 + nj * 16 + l15;
      int rowb = row0 + wr * 64 + mi * 16 + lhi * 4;
      if (kp != nullptr && colb >= 1024) {
        if (colb < 1280) {
          int gg = (colb - 1024) >> 6, d = (colb - 1024) & 63;
          bf16_t* kdst = kp + ((size_t)gg * 4096 + rowb) * 64 + d;
#pragma unroll
          for (int r2 = 0; r2 < 4; ++r2)
            kdst[r2 * 64] = (bf16_t)(acc[mi][nj][r2] * KSCALE);
        } else {
          union { bf16_t hh[4]; uint64_t u; } a;
#pragma unroll
          for (int r2 = 0; r2 < 4; ++r2) a.hh[r2] = (bf16_t)acc[mi][nj][r2];
          *reinterpret_cast<uint64_t*>(vt + (size_t)(colb - 1280) * 4096 + rowb) = a.u;
        }
      } else {
#pragma unroll
        for (int r2 = 0; r2 < 4; ++r2)
          C[(size_t)(rowb + r2) * N + colb] = (T)acc[mi][nj][r2];
      }
    }
}

// ---------------------------------------------------------------- flash attention (causal GQA)
// Pair-and-split balance (1024 equal blocks, 4 waves KV-split, barrier-free).
// K pre-scaled by 0.125*log2(e) -> P = exp2(st) directly (no FMA pass; softmax
// normalization is scale-invariant). nj-streamed QKT->exp->pack pipeline.
__global__ __launch_bounds__(256, 4) void attn_kernel(const bf16_t* __restrict__ qkv,
                                                      const bf16_t* __restrict__ kp,
                                                      const bf16_t* __restrict__ vt,
                                                      bf16_t* __restrict__ ctx,
                                                      float* __restrict__ Opart,
                                                      float* __restrict__ lpart) {
  int tid = threadIdx.x, lane = tid & 63, w = tid >> 6;
  int l15 = lane & 15, lhi = lane >> 4;
  int e = l15 & 7;
  int bid = blockIdx.x;
  int h = bid & 15, qq = bid >> 4;
  int p = qq >> 1, half = qq & 1;
  int g = h >> 2;

  __shared__ alignas(16) char smem[34816 + 256];
  char* pbuf = smem + w * 8192;
  float* ilbuf = (float*)(smem + 34816);

  const bf16_t* kbase = kp + (size_t)g * 4096 * 64;
  const bf16_t* vbase = vt + (size_t)g * 64 * 4096;

  auto runPhase = [&](int tile, int sbeg, int send, bool fin,
                      float* Oslot, float* lslot) {
    int r0 = tile * 64;
    bf16x8 qf[4][2];
#pragma unroll
    for (int mi = 0; mi < 4; ++mi)
#pragma unroll
      for (int ks = 0; ks < 2; ++ks)
        qf[mi][ks] = *reinterpret_cast<const bf16x8*>(
            qkv + (size_t)(r0 + mi * 16 + l15) * 1536 + h * 64 + ks * 32 + lhi * 8);

    f32x4 O[4][4] = {};
    float lsum[4] = {0.f, 0.f, 0.f, 0.f};

    for (int step = sbeg + w; step < send; step += 4) {
      int j0 = step * 64;
      // ---- K fragments, direct from L2 (all issued up front)
      bf16x8 kf[4][2];
#pragma unroll
      for (int nj = 0; nj < 4; ++nj) {
        const bf16_t* kr = kbase + (size_t)(j0 + nj * 16 + l15) * 64 + lhi * 8;
        kf[nj][0] = *reinterpret_cast<const bf16x8*>(kr);
        kf[nj][1] = *reinterpret_cast<const bf16x8*>(kr + 32);
      }
      bool diag = (j0 + 64 > r0);
      // ---- streamed QKT -> exp2 -> pack -> P-LDS, one nj-group at a time
      //      (VALU of group nj overlaps MFMA of group nj+1)
#pragma unroll
      for (int nj = 0; nj < 4; ++nj) {
        f32x4 stn[4];
#pragma unroll
        for (int mi = 0; mi < 4; ++mi) {
          f32x4 t = {0.f, 0.f, 0.f, 0.f};
          t = MFMA16(kf[nj][0], qf[mi][0], t);
          t = MFMA16(kf[nj][1], qf[mi][1], t);
          stn[mi] = t;
        }
        if (diag) {
#pragma unroll
          for (int mi = 0; mi < 4; ++mi)
#pragma unroll
            for (int r = 0; r < 4; ++r) {
              int key = j0 + nj * 16 + lhi * 4 + r;
              int qr  = r0 + mi * 16 + l15;
              if (key > qr) stn[mi][r] = -1e30f;
            }
        }
        int sw = (nj * 2 + (lhi >> 1)) ^ e;
#pragma unroll
        for (int mi = 0; mi < 4; ++mi) {
          float ls = 0.f;
          union { bf16_t hh[4]; uint64_t u; } a;
#pragma unroll
          for (int r = 0; r < 4; ++r) {
            float pv = exp2f(stn[mi][r]);   // K pre-scaled; bias-free (invariant)
            ls += pv;
            a.hh[r] = (bf16_t)pv;
          }
          lsum[mi] += ls;
          char* prow = pbuf + (mi * 16 + l15) * 128 + ((lhi & 1) << 3);
          *reinterpret_cast<uint64_t*>(prow + sw * 16) = a.u;
        }
      }
      // ---- PV: A = P (qrow=l15), B = V^T (hd=l15)
      bf16x8 ap[4][2];
#pragma unroll
      for (int mi = 0; mi < 4; ++mi)
#pragma unroll
        for (int ks = 0; ks < 2; ++ks)
          ap[mi][ks] = *reinterpret_cast<const bf16x8*>(
              pbuf + (mi * 16 + l15) * 128 + (((ks * 4 + lhi) ^ e) << 4));
#pragma unroll
      for (int h4 = 0; h4 < 4; ++h4) {
        const bf16_t* vr = vbase + (size_t)(h4 * 16 + l15) * 4096 + j0 + lhi * 8;
        bf16x8 v0 = *reinterpret_cast<const bf16x8*>(vr);
        bf16x8 v1 = *reinterpret_cast<const bf16x8*>(vr + 32);
#pragma unroll
        for (int mi = 0; mi < 4; ++mi) {
          O[mi][h4] = MFMA16(ap[mi][0], v0, O[mi][h4]);
          O[mi][h4] = MFMA16(ap[mi][1], v1, O[mi][h4]);
        }
      }
    }

    // ---- in-block combine (regions overlay dead pbufs)
    auto WRr = [&](int r) {
      float* ob = (float*)(smem + r * 17408) + lane * 64;
#pragma unroll
      for (int mi = 0; mi < 4; ++mi)
#pragma unroll
        for (int h4 = 0; h4 < 4; ++h4)
          *reinterpret_cast<f32x4*>(ob + (((mi * 4 + h4) ^ e) << 2)) = O[mi][h4];
      f32x4 lv = {lsum[0], lsum[1], lsum[2], lsum[3]};
      *reinterpret_cast<f32x4*>(smem + r * 17408 + 16384 + lane * 16) = lv;
    };
    auto RDr = [&](int r) {
      const float* ob = (const float*)(smem + r * 17408) + lane * 64;
#pragma unroll
      for (int mi = 0; mi < 4; ++mi)
#pragma unroll
        for (int h4 = 0; h4 < 4; ++h4)
          O[mi][h4] += *reinterpret_cast<const f32x4*>(ob + (((mi * 4 + h4) ^ e) << 2));
      f32x4 lv = *reinterpret_cast<const f32x4*>(smem + r * 17408 + 16384 + lane * 16);
#pragma unroll
      for (int mi = 0; mi < 4; ++mi) lsum[mi] += lv[mi];
    };

    __syncthreads();
    if (w == 1) WRr(0);
    if (w == 2) WRr(1);
    __syncthreads();
    if (w == 0) { RDr(0); RDr(1); }
    __syncthreads();
    if (w == 3) WRr(0);
    __syncthreads();
    if (w == 0) {
      RDr(0);
#pragma unroll
      for (int mi = 0; mi < 4; ++mi) {
        float l = lsum[mi];
        l += __shfl_xor(l, 16);
        l += __shfl_xor(l, 32);
        if (fin) {
          if (lhi == 0) ilbuf[mi * 16 + l15] = 1.0f / l;
        } else {
          if (lhi == 0) lslot[mi * 16 + l15] = l;
        }
      }
      if (fin) {
#pragma unroll
        for (int mi = 0; mi < 4; ++mi) {
          f32x4 il = *reinterpret_cast<const f32x4*>(ilbuf + mi * 16 + lhi * 4);
#pragma unroll
          for (int h4 = 0; h4 < 4; ++h4)
#pragma unroll
            for (int r = 0; r < 4; ++r) O[mi][h4][r] *= il[r];
        }
      }
    }
    __syncthreads();   // w0 done with LDS; release pbuf for next phase
    if (w == 0) {
      if (fin) {
#pragma unroll
        for (int mi = 0; mi < 4; ++mi)
#pragma unroll
          for (int h4 = 0; h4 < 4; ++h4)
#pragma unroll
            for (int r = 0; r < 4; ++r) {
              int row = r0 + mi * 16 + lhi * 4 + r;
              ctx[(size_t)row * 1024 + h * 64 + h4 * 16 + l15] = (bf16_t)O[mi][h4][r];
            }
      } else {
#pragma unroll
        for (int mi = 0; mi < 4; ++mi)
#pragma unroll
          for (int h4 = 0; h4 < 4; ++h4)
            *reinterpret_cast<f32x4*>(Oslot + (mi * 4 + h4) * 256 + lane * 4) = O[mi][h4];
      }
    }
  };

  if (half == 0) {
    bool fin = (p == 31);
    int u = (30 - p) * 16 + h;
    float* Os = fin ? nullptr : Opart + ((size_t)u * 2 + 0) * 4096;
    float* ls = fin ? nullptr : lpart + ((size_t)u * 2 + 0) * 64;
    runPhase(63 - p, 0, 33, fin, Os, ls);
  } else {
    if (p < 31) {
      int u = (30 - p) * 16 + h;
      runPhase(63 - p, 33, 64 - p, false,
               Opart + ((size_t)u * 2 + 1) * 4096, lpart + ((size_t)u * 2 + 1) * 64);
    }
    runPhase(p, 0, p + 1, true, nullptr, nullptr);
  }
}

// ---------------------------------------------------------------- combine split-tile partials
__global__ __launch_bounds__(256) void norm_combine(const float* __restrict__ Opart,
                                                    const float* __restrict__ lpart,
                                                    bf16_t* __restrict__ ctx) {
  int u = blockIdx.x;
  int T = 33 + (u >> 4), h = u & 15;
  int t = threadIdx.x;
  int lane = t & 63, mi = t >> 6;
  int l15 = lane & 15, lhi = lane >> 4;
  const float* O0 = Opart + (size_t)u * 2 * 4096;
  const float* O1 = O0 + 4096;
  const float* l0 = lpart + (size_t)u * 2 * 64;
  const float* l1 = l0 + 64;
  float il[4];
#pragma unroll
  for (int r = 0; r < 4; ++r) {
    int row = mi * 16 + lhi * 4 + r;
    il[r] = 1.0f / (l0[row] + l1[row]);
  }
#pragma unroll
  for (int h4 = 0; h4 < 4; ++h4) {
    int idx = (mi * 4 + h4) * 256 + lane * 4;
    f32x4 a = *reinterpret_cast<const f32x4*>(O0 + idx);
    f32x4 b = *reinterpret_cast<const f32x4*>(O1 + idx);
#pragma unroll
    for (int r = 0; r < 4; ++r) {
      int row = mi * 16 + lhi * 4 + r;
      ctx[(size_t)(T * 64 + row) * 1024 + h * 64 + h4 * 16 + l15] =
          (bf16_t)((a[r] + b[r]) * il[r]);
    }
  }
}

// ---------------------------------------------------------------- launch
extern "C" void kernel_launch(void* const* d_in, const int* in_sizes, int n_in,
                              void* d_out, int out_size, void* d_ws, size_t ws_size,
                              hipStream_t stream) {
  const float* x  = (const float*)d_in[0];
  const float* wq = (const float*)d_in[1];
  const float* wk = (const float*)d_in[2];
  const float* wv = (const float*)d_in[3];
  const float* wo = (const float*)d_in[4];
  float* out = (float*)d_out;

  char* ws = (char*)d_ws;
  size_t off = 0;
  auto alloc = [&](size_t b) {
    char* p = ws + off;
    off += (b + 255) & ~(size_t)255;
    return p;
  };
  bf16_t* wob  = (bf16_t*)alloc((size_t)1024 * 1024 * 2);
  bf16_t* qkv  = (bf16_t*)alloc((size_t)4096 * 1536 * 2);
  bf16_t* vtb  = (bf16_t*)alloc((size_t)256 * 4096 * 2);
  bf16_t* kpb  = (bf16_t*)alloc((size_t)4 * 4096 * 64 * 2);
  bf16_t* ctx  = (bf16_t*)alloc((size_t)4096 * 1024 * 2);
  size_t scratch_base = off;
  bf16_t* xb   = (bf16_t*)alloc((size_t)4096 * 1024 * 2);
  bf16_t* wqkv = (bf16_t*)alloc((size_t)1536 * 1024 * 2);
  float* Opart = (float*)(ws + scratch_base);
  float* lpart = Opart + (size_t)496 * 2 * 4096;

  cvt_all<<<3328, 256, 0, stream>>>(x, wq, wk, wv, wo, xb, wqkv, wob);
  gemm_bt<bf16_t><<<dim3(12, 32), 256, 0, stream>>>(xb, wqkv, qkv, 4096, 1536, 1024,
                                                    kpb, vtb);
  attn_kernel<<<1024, 256, 0, stream>>>(qkv, kpb, vtb, ctx, Opart, lpart);
  norm_combine<<<496, 256, 0, stream>>>(Opart, lpart, ctx);
  gemm_bt<float><<<dim3(8, 32), 256, 0, stream>>>(ctx, wob, out, 4096, 1024, 1024,
                                                  nullptr, nullptr);
}

// Round 9
// 143.601 us; speedup vs baseline: 2.2115x; 2.2115x over previous
//
#include <hip/hip_runtime.h>

typedef __bf16 bf16_t;
typedef __bf16 bf16x8 __attribute__((ext_vector_type(8)));
typedef float  f32x4  __attribute__((ext_vector_type(4)));

#define MFMA16(a, b, c) __builtin_amdgcn_mfma_f32_16x16x32_bf16((a), (b), (c), 0, 0, 0)

__device__ __forceinline__ void gload_lds16(const void* g, void* l) {
  __builtin_amdgcn_global_load_lds((__attribute__((address_space(1))) void*)(g),
                                   (__attribute__((address_space(3))) void*)(l),
                                   16, 0, 0);
}

// ---------------------------------------------------------------- fused convert (x, wq, wk, wv, wo)
__global__ __launch_bounds__(256) void cvt_all(const float* __restrict__ x,
                                               const float* __restrict__ wq,
                                               const float* __restrict__ wk,
                                               const float* __restrict__ wv,
                                               const float* __restrict__ wo,
                                               bf16_t* __restrict__ xb,
                                               bf16_t* __restrict__ wqkv,
                                               bf16_t* __restrict__ wob) {
  int i = (blockIdx.x * 256 + threadIdx.x) * 8;
  const float* src;
  bf16_t* dst;
  int off;
  if (i < 4194304)      { src = x;  dst = xb;             off = i; }
  else if (i < 5242880) { src = wq; dst = wqkv;           off = i - 4194304; }
  else if (i < 5505024) { src = wk; dst = wqkv + 1048576; off = i - 5242880; }
  else if (i < 5767168) { src = wv; dst = wqkv + 1310720; off = i - 5505024; }
  else                  { src = wo; dst = wob;            off = i - 5767168; }
  const float4* pp = reinterpret_cast<const float4*>(src + off);
  float4 a = pp[0], b = pp[1];
  bf16x8 v;
  v[0] = (bf16_t)a.x; v[1] = (bf16_t)a.y; v[2] = (bf16_t)a.z; v[3] = (bf16_t)a.w;
  v[4] = (bf16_t)b.x; v[5] = (bf16_t)b.y; v[6] = (bf16_t)b.z; v[7] = (bf16_t)b.w;
  *reinterpret_cast<bf16x8*>(dst + off) = v;
}

// ---------------------------------------------------------------- GEMM  C[M,N] = A[M,K] * B[N,K]^T
// Dual-write epilogue when kp/vt non-null: cols [1024,1280) -> kp[4][4096][64]
// PRE-SCALED by 0.125*log2(e) (attn uses exp2 directly); cols [1280,1536) ->
// vt[256][4096] transposed.
template <typename T>
__global__ __launch_bounds__(256) void gemm_bt(const bf16_t* __restrict__ A,
                                               const bf16_t* __restrict__ B,
                                               T* __restrict__ C,
                                               int M, int N, int K,
                                               bf16_t* __restrict__ kp,
                                               bf16_t* __restrict__ vt) {
  constexpr int BK = 64;
  int tid  = threadIdx.x;
  int lane = tid & 63, w = tid >> 6;
  int wr = w >> 1, wc = w & 1;
  int l15 = lane & 15, lhi = lane >> 4;
  int row0 = blockIdx.y * 128, col0 = blockIdx.x * 128;

  __shared__ alignas(16) char smem[128 * BK * 2 * 2];
  char* sA = smem;
  char* sB = smem + 128 * BK * 2;

  f32x4 acc[4][4] = {};

  for (int k0 = 0; k0 < K; k0 += BK) {
#pragma unroll
    for (int i = 0; i < 4; ++i) {
      int c = i * 256 + tid;
      int r = c >> 3, kc = c & 7;
      int kk = k0 + ((kc ^ (r & 7)) << 3);
      gload_lds16(A + (size_t)(row0 + r) * K + kk, sA + c * 16);
      gload_lds16(B + (size_t)(col0 + r) * K + kk, sB + c * 16);
    }
    __syncthreads();
#pragma unroll
    for (int s = 0; s < 2; ++s) {
      bf16x8 af[4], bfr[4];
#pragma unroll
      for (int mi = 0; mi < 4; ++mi) {
        int r = wr * 64 + mi * 16 + l15;
        af[mi] = *reinterpret_cast<const bf16x8*>(
            sA + r * 128 + (((s * 4 + lhi) ^ (r & 7)) << 4));
      }
#pragma unroll
      for (int nj = 0; nj < 4; ++nj) {
        int r = wc * 64 + nj * 16 + l15;
        bfr[nj] = *reinterpret_cast<const bf16x8*>(
            sB + r * 128 + (((s * 4 + lhi) ^ (r & 7)) << 4));
      }
#pragma unroll
      for (int mi = 0; mi < 4; ++mi)
#pragma unroll
        for (int nj = 0; nj < 4; ++nj)
          acc[mi][nj] = MFMA16(af[mi], bfr[nj], acc[mi][nj]);
    }
    __syncthreads();
  }

  const float KSCALE = 0.18033688f;   // 0.125 * log2(e)
#pragma unroll
  for (int mi = 0; mi < 4; ++mi)
#pragma unroll
    for (int nj = 0; nj < 4; ++nj) {
      int colb = col0 + wc * 64 + nj * 16 + l15;
      int rowb = row0 + wr * 64 + mi * 16 + lhi * 4;
      if (kp != nullptr && colb >= 1024) {
        if (colb < 1280) {
          int gg = (colb - 1024) >> 6, d = (colb - 1024) & 63;
          bf16_t* kdst = kp + ((size_t)gg * 4096 + rowb) * 64 + d;
#pragma unroll
          for (int r2 = 0; r2 < 4; ++r2)
            kdst[r2 * 64] = (bf16_t)(acc[mi][nj][r2] * KSCALE);
        } else {
          union { bf16_t hh[4]; uint64_t u; } a;
#pragma unroll
          for (int r2 = 0; r2 < 4; ++r2) a.hh[r2] = (bf16_t)acc[mi][nj][r2];
          *reinterpret_cast<uint64_t*>(vt + (size_t)(colb - 1280) * 4096 + rowb) = a.u;
        }
      } else {
#pragma unroll
        for (int r2 = 0; r2 < 4; ++r2)
          C[(size_t)(rowb + r2) * N + colb] = (T)acc[mi][nj][r2];
      }
    }
}

// ---------------------------------------------------------------- flash attention (causal GQA)
// Pair-and-split balance (1024 equal blocks, 4 waves KV-split, barrier-free).
// K pre-scaled by 0.125*log2(e) -> P = exp2(st) directly (bias-free; softmax
// normalization is scale-invariant). nj-streamed QKT->exp->pack pipeline.
// launch_bounds (256,2): empirical hipcc rule caps VGPR at ~256/w — w=2 gives
// the 128 VGPR this kernel needs; w=4 caused 64-VGPR spill storms (R6/R8).
__global__ __launch_bounds__(256, 2) void attn_kernel(const bf16_t* __restrict__ qkv,
                                                      const bf16_t* __restrict__ kp,
                                                      const bf16_t* __restrict__ vt,
                                                      bf16_t* __restrict__ ctx,
                                                      float* __restrict__ Opart,
                                                      float* __restrict__ lpart) {
  int tid = threadIdx.x, lane = tid & 63, w = tid >> 6;
  int l15 = lane & 15, lhi = lane >> 4;
  int e = l15 & 7;
  int bid = blockIdx.x;
  int h = bid & 15, qq = bid >> 4;
  int p = qq >> 1, half = qq & 1;
  int g = h >> 2;

  __shared__ alignas(16) char smem[34816 + 256];
  char* pbuf = smem + w * 8192;
  float* ilbuf = (float*)(smem + 34816);

  const bf16_t* kbase = kp + (size_t)g * 4096 * 64;
  const bf16_t* vbase = vt + (size_t)g * 64 * 4096;

  auto runPhase = [&](int tile, int sbeg, int send, bool fin,
                      float* Oslot, float* lslot) {
    int r0 = tile * 64;
    bf16x8 qf[4][2];
#pragma unroll
    for (int mi = 0; mi < 4; ++mi)
#pragma unroll
      for (int ks = 0; ks < 2; ++ks)
        qf[mi][ks] = *reinterpret_cast<const bf16x8*>(
            qkv + (size_t)(r0 + mi * 16 + l15) * 1536 + h * 64 + ks * 32 + lhi * 8);

    f32x4 O[4][4] = {};
    float lsum[4] = {0.f, 0.f, 0.f, 0.f};

    for (int step = sbeg + w; step < send; step += 4) {
      int j0 = step * 64;
      // ---- K fragments, direct from L2 (all issued up front)
      bf16x8 kf[4][2];
#pragma unroll
      for (int nj = 0; nj < 4; ++nj) {
        const bf16_t* kr = kbase + (size_t)(j0 + nj * 16 + l15) * 64 + lhi * 8;
        kf[nj][0] = *reinterpret_cast<const bf16x8*>(kr);
        kf[nj][1] = *reinterpret_cast<const bf16x8*>(kr + 32);
      }
      bool diag = (j0 + 64 > r0);
      // ---- streamed QKT -> exp2 -> pack -> P-LDS, one nj-group at a time
      //      (VALU of group nj overlaps MFMA of group nj+1)
#pragma unroll
      for (int nj = 0; nj < 4; ++nj) {
        f32x4 stn[4];
#pragma unroll
        for (int mi = 0; mi < 4; ++mi) {
          f32x4 t = {0.f, 0.f, 0.f, 0.f};
          t = MFMA16(kf[nj][0], qf[mi][0], t);
          t = MFMA16(kf[nj][1], qf[mi][1], t);
          stn[mi] = t;
        }
        if (diag) {
#pragma unroll
          for (int mi = 0; mi < 4; ++mi)
#pragma unroll
            for (int r = 0; r < 4; ++r) {
              int key = j0 + nj * 16 + lhi * 4 + r;
              int qr  = r0 + mi * 16 + l15;
              if (key > qr) stn[mi][r] = -1e30f;
            }
        }
        int sw = (nj * 2 + (lhi >> 1)) ^ e;
#pragma unroll
        for (int mi = 0; mi < 4; ++mi) {
          float ls = 0.f;
          union { bf16_t hh[4]; uint64_t u; } a;
#pragma unroll
          for (int r = 0; r < 4; ++r) {
            float pv = exp2f(stn[mi][r]);   // K pre-scaled; bias-free (invariant)
            ls += pv;
            a.hh[r] = (bf16_t)pv;
          }
          lsum[mi] += ls;
          char* prow = pbuf + (mi * 16 + l15) * 128 + ((lhi & 1) << 3);
          *reinterpret_cast<uint64_t*>(prow + sw * 16) = a.u;
        }
      }
      // ---- PV: A = P (qrow=l15), B = V^T (hd=l15)
      bf16x8 ap[4][2];
#pragma unroll
      for (int mi = 0; mi < 4; ++mi)
#pragma unroll
        for (int ks = 0; ks < 2; ++ks)
          ap[mi][ks] = *reinterpret_cast<const bf16x8*>(
              pbuf + (mi * 16 + l15) * 128 + (((ks * 4 + lhi) ^ e) << 4));
#pragma unroll
      for (int h4 = 0; h4 < 4; ++h4) {
        const bf16_t* vr = vbase + (size_t)(h4 * 16 + l15) * 4096 + j0 + lhi * 8;
        bf16x8 v0 = *reinterpret_cast<const bf16x8*>(vr);
        bf16x8 v1 = *reinterpret_cast<const bf16x8*>(vr + 32);
#pragma unroll
        for (int mi = 0; mi < 4; ++mi) {
          O[mi][h4] = MFMA16(ap[mi][0], v0, O[mi][h4]);
          O[mi][h4] = MFMA16(ap[mi][1], v1, O[mi][h4]);
        }
      }
    }

    // ---- in-block combine (regions overlay dead pbufs)
    auto WRr = [&](int r) {
      float* ob = (float*)(smem + r * 17408) + lane * 64;
#pragma unroll
      for (int mi = 0; mi < 4; ++mi)
#pragma unroll
        for (int h4 = 0; h4 < 4; ++h4)
          *reinterpret_cast<f32x4*>(ob + (((mi * 4 + h4) ^ e) << 2)) = O[mi][h4];
      f32x4 lv = {lsum[0], lsum[1], lsum[2], lsum[3]};
      *reinterpret_cast<f32x4*>(smem + r * 17408 + 16384 + lane * 16) = lv;
    };
    auto RDr = [&](int r) {
      const float* ob = (const float*)(smem + r * 17408) + lane * 64;
#pragma unroll
      for (int mi = 0; mi < 4; ++mi)
#pragma unroll
        for (int h4 = 0; h4 < 4; ++h4)
          O[mi][h4] += *reinterpret_cast<const f32x4*>(ob + (((mi * 4 + h4) ^ e) << 2));
      f32x4 lv = *reinterpret_cast<const f32x4*>(smem + r * 17408 + 16384 + lane * 16);
#pragma unroll
      for (int mi = 0; mi < 4; ++mi) lsum[mi] += lv[mi];
    };

    __syncthreads();
    if (w == 1) WRr(0);
    if (w == 2) WRr(1);
    __syncthreads();
    if (w == 0) { RDr(0); RDr(1); }
    __syncthreads();
    if (w == 3) WRr(0);
    __syncthreads();
    if (w == 0) {
      RDr(0);
#pragma unroll
      for (int mi = 0; mi < 4; ++mi) {
        float l = lsum[mi];
        l += __shfl_xor(l, 16);
        l += __shfl_xor(l, 32);
        if (fin) {
          if (lhi == 0) ilbuf[mi * 16 + l15] = 1.0f / l;
        } else {
          if (lhi == 0) lslot[mi * 16 + l15] = l;
        }
      }
      if (fin) {
#pragma unroll
        for (int mi = 0; mi < 4; ++mi) {
          f32x4 il = *reinterpret_cast<const f32x4*>(ilbuf + mi * 16 + lhi * 4);
#pragma unroll
          for (int h4 = 0; h4 < 4; ++h4)
#pragma unroll
            for (int r = 0; r < 4; ++r) O[mi][h4][r] *= il[r];
        }
      }
    }
    __syncthreads();   // w0 done with LDS; release pbuf for next phase
    if (w == 0) {
      if (fin) {
#pragma unroll
        for (int mi = 0; mi < 4; ++mi)
#pragma unroll
          for (int h4 = 0; h4 < 4; ++h4)
#pragma unroll
            for (int r = 0; r < 4; ++r) {
              int row = r0 + mi * 16 + lhi * 4 + r;
              ctx[(size_t)row * 1024 + h * 64 + h4 * 16 + l15] = (bf16_t)O[mi][h4][r];
            }
      } else {
#pragma unroll
        for (int mi = 0; mi < 4; ++mi)
#pragma unroll
          for (int h4 = 0; h4 < 4; ++h4)
            *reinterpret_cast<f32x4*>(Oslot + (mi * 4 + h4) * 256 + lane * 4) = O[mi][h4];
      }
    }
  };

  if (half == 0) {
    bool fin = (p == 31);
    int u = (30 - p) * 16 + h;
    float* Os = fin ? nullptr : Opart + ((size_t)u * 2 + 0) * 4096;
    float* ls = fin ? nullptr : lpart + ((size_t)u * 2 + 0) * 64;
    runPhase(63 - p, 0, 33, fin, Os, ls);
  } else {
    if (p < 31) {
      int u = (30 - p) * 16 + h;
      runPhase(63 - p, 33, 64 - p, false,
               Opart + ((size_t)u * 2 + 1) * 4096, lpart + ((size_t)u * 2 + 1) * 64);
    }
    runPhase(p, 0, p + 1, true, nullptr, nullptr);
  }
}

// ---------------------------------------------------------------- combine split-tile partials
__global__ __launch_bounds__(256) void norm_combine(const float* __restrict__ Opart,
                                                    const float* __restrict__ lpart,
                                                    bf16_t* __restrict__ ctx) {
  int u = blockIdx.x;
  int T = 33 + (u >> 4), h = u & 15;
  int t = threadIdx.x;
  int lane = t & 63, mi = t >> 6;
  int l15 = lane & 15, lhi = lane >> 4;
  const float* O0 = Opart + (size_t)u * 2 * 4096;
  const float* O1 = O0 + 4096;
  const float* l0 = lpart + (size_t)u * 2 * 64;
  const float* l1 = l0 + 64;
  float il[4];
#pragma unroll
  for (int r = 0; r < 4; ++r) {
    int row = mi * 16 + lhi * 4 + r;
    il[r] = 1.0f / (l0[row] + l1[row]);
  }
#pragma unroll
  for (int h4 = 0; h4 < 4; ++h4) {
    int idx = (mi * 4 + h4) * 256 + lane * 4;
    f32x4 a = *reinterpret_cast<const f32x4*>(O0 + idx);
    f32x4 b = *reinterpret_cast<const f32x4*>(O1 + idx);
#pragma unroll
    for (int r = 0; r < 4; ++r) {
      int row = mi * 16 + lhi * 4 + r;
      ctx[(size_t)(T * 64 + row) * 1024 + h * 64 + h4 * 16 + l15] =
          (bf16_t)((a[r] + b[r]) * il[r]);
    }
  }
}

// ---------------------------------------------------------------- launch
extern "C" void kernel_launch(void* const* d_in, const int* in_sizes, int n_in,
                              void* d_out, int out_size, void* d_ws, size_t ws_size,
                              hipStream_t stream) {
  const float* x  = (const float*)d_in[0];
  const float* wq = (const float*)d_in[1];
  const float* wk = (const float*)d_in[2];
  const float* wv = (const float*)d_in[3];
  const float* wo = (const float*)d_in[4];
  float* out = (float*)d_out;

  char* ws = (char*)d_ws;
  size_t off = 0;
  auto alloc = [&](size_t b) {
    char* p = ws + off;
    off += (b + 255) & ~(size_t)255;
    return p;
  };
  bf16_t* wob  = (bf16_t*)alloc((size_t)1024 * 1024 * 2);
  bf16_t* qkv  = (bf16_t*)alloc((size_t)4096 * 1536 * 2);
  bf16_t* vtb  = (bf16_t*)alloc((size_t)256 * 4096 * 2);
  bf16_t* kpb  = (bf16_t*)alloc((size_t)4 * 4096 * 64 * 2);
  bf16_t* ctx  = (bf16_t*)alloc((size_t)4096 * 1024 * 2);
  size_t scratch_base = off;
  bf16_t* xb   = (bf16_t*)alloc((size_t)4096 * 1024 * 2);
  bf16_t* wqkv = (bf16_t*)alloc((size_t)1536 * 1024 * 2);
  float* Opart = (float*)(ws + scratch_base);
  float* lpart = Opart + (size_t)496 * 2 * 4096;

  cvt_all<<<3328, 256, 0, stream>>>(x, wq, wk, wv, wo, xb, wqkv, wob);
  gemm_bt<bf16_t><<<dim3(12, 32), 256, 0, stream>>>(xb, wqkv, qkv, 4096, 1536, 1024,
                                                    kpb, vtb);
  attn_kernel<<<1024, 256, 0, stream>>>(qkv, kpb, vtb, ctx, Opart, lpart);
  norm_combine<<<496, 256, 0, stream>>>(Opart, lpart, ctx);
  gemm_bt<float><<<dim3(8, 32), 256, 0, stream>>>(ctx, wob, out, 4096, 1024, 1024,
                                                  nullptr, nullptr);
}

// Round 10
// 143.328 us; speedup vs baseline: 2.2157x; 1.0019x over previous
//
#include <hip/hip_runtime.h>

typedef __bf16 bf16_t;
typedef __bf16 bf16x8 __attribute__((ext_vector_type(8)));
typedef float  f32x4  __attribute__((ext_vector_type(4)));

#define MFMA16(a, b, c) __builtin_amdgcn_mfma_f32_16x16x32_bf16((a), (b), (c), 0, 0, 0)

__device__ __forceinline__ void gload_lds16(const void* g, void* l) {
  __builtin_amdgcn_global_load_lds((__attribute__((address_space(1))) void*)(g),
                                   (__attribute__((address_space(3))) void*)(l),
                                   16, 0, 0);
}

// ---------------------------------------------------------------- fused convert (x, wq, wk, wv, wo)
__global__ __launch_bounds__(256) void cvt_all(const float* __restrict__ x,
                                               const float* __restrict__ wq,
                                               const float* __restrict__ wk,
                                               const float* __restrict__ wv,
                                               const float* __restrict__ wo,
                                               bf16_t* __restrict__ xb,
                                               bf16_t* __restrict__ wqkv,
                                               bf16_t* __restrict__ wob) {
  int i = (blockIdx.x * 256 + threadIdx.x) * 8;
  const float* src;
  bf16_t* dst;
  int off;
  if (i < 4194304)      { src = x;  dst = xb;             off = i; }
  else if (i < 5242880) { src = wq; dst = wqkv;           off = i - 4194304; }
  else if (i < 5505024) { src = wk; dst = wqkv + 1048576; off = i - 5242880; }
  else if (i < 5767168) { src = wv; dst = wqkv + 1310720; off = i - 5505024; }
  else                  { src = wo; dst = wob;            off = i - 5767168; }
  const float4* pp = reinterpret_cast<const float4*>(src + off);
  float4 a = pp[0], b = pp[1];
  bf16x8 v;
  v[0] = (bf16_t)a.x; v[1] = (bf16_t)a.y; v[2] = (bf16_t)a.z; v[3] = (bf16_t)a.w;
  v[4] = (bf16_t)b.x; v[5] = (bf16_t)b.y; v[6] = (bf16_t)b.z; v[7] = (bf16_t)b.w;
  *reinterpret_cast<bf16x8*>(dst + off) = v;
}

// ---------------------------------------------------------------- GEMM  C[M,N] = A[M,K] * B[N,K]^T
// Dual-write epilogue when kp/vt non-null: cols [1024,1280) -> kp[4][4096][64]
// PRE-SCALED by 0.125*log2(e) (attn uses exp2 directly); cols [1280,1536) ->
// vt[256][4096] transposed.
template <typename T>
__global__ __launch_bounds__(256) void gemm_bt(const bf16_t* __restrict__ A,
                                               const bf16_t* __restrict__ B,
                                               T* __restrict__ C,
                                               int M, int N, int K,
                                               bf16_t* __restrict__ kp,
                                               bf16_t* __restrict__ vt) {
  constexpr int BK = 64;
  int tid  = threadIdx.x;
  int lane = tid & 63, w = tid >> 6;
  int wr = w >> 1, wc = w & 1;
  int l15 = lane & 15, lhi = lane >> 4;
  int row0 = blockIdx.y * 128, col0 = blockIdx.x * 128;

  __shared__ alignas(16) char smem[128 * BK * 2 * 2];
  char* sA = smem;
  char* sB = smem + 128 * BK * 2;

  f32x4 acc[4][4] = {};

  for (int k0 = 0; k0 < K; k0 += BK) {
#pragma unroll
    for (int i = 0; i < 4; ++i) {
      int c = i * 256 + tid;
      int r = c >> 3, kc = c & 7;
      int kk = k0 + ((kc ^ (r & 7)) << 3);
      gload_lds16(A + (size_t)(row0 + r) * K + kk, sA + c * 16);
      gload_lds16(B + (size_t)(col0 + r) * K + kk, sB + c * 16);
    }
    __syncthreads();
#pragma unroll
    for (int s = 0; s < 2; ++s) {
      bf16x8 af[4], bfr[4];
#pragma unroll
      for (int mi = 0; mi < 4; ++mi) {
        int r = wr * 64 + mi * 16 + l15;
        af[mi] = *reinterpret_cast<const bf16x8*>(
            sA + r * 128 + (((s * 4 + lhi) ^ (r & 7)) << 4));
      }
#pragma unroll
      for (int nj = 0; nj < 4; ++nj) {
        int r = wc * 64 + nj * 16 + l15;
        bfr[nj] = *reinterpret_cast<const bf16x8*>(
            sB + r * 128 + (((s * 4 + lhi) ^ (r & 7)) << 4));
      }
#pragma unroll
      for (int mi = 0; mi < 4; ++mi)
#pragma unroll
        for (int nj = 0; nj < 4; ++nj)
          acc[mi][nj] = MFMA16(af[mi], bfr[nj], acc[mi][nj]);
    }
    __syncthreads();
  }

  const float KSCALE = 0.18033688f;   // 0.125 * log2(e)
#pragma unroll
  for (int mi = 0; mi < 4; ++mi)
#pragma unroll
    for (int nj = 0; nj < 4; ++nj) {
      int colb = col0 + wc * 64 + nj * 16 + l15;
      int rowb = row0 + wr * 64 + mi * 16 + lhi * 4;
      if (kp != nullptr && colb >= 1024) {
        if (colb < 1280) {
          int gg = (colb - 1024) >> 6, d = (colb - 1024) & 63;
          bf16_t* kdst = kp + ((size_t)gg * 4096 + rowb) * 64 + d;
#pragma unroll
          for (int r2 = 0; r2 < 4; ++r2)
            kdst[r2 * 64] = (bf16_t)(acc[mi][nj][r2] * KSCALE);
        } else {
          union { bf16_t hh[4]; uint64_t u; } a;
#pragma unroll
          for (int r2 = 0; r2 < 4; ++r2) a.hh[r2] = (bf16_t)acc[mi][nj][r2];
          *reinterpret_cast<uint64_t*>(vt + (size_t)(colb - 1280) * 4096 + rowb) = a.u;
        }
      } else {
#pragma unroll
        for (int r2 = 0; r2 < 4; ++r2)
          C[(size_t)(rowb + r2) * N + colb] = (T)acc[mi][nj][r2];
      }
    }
}

// ---------------------------------------------------------------- flash attention (causal GQA)
// Pair-and-split balance (1024 equal blocks, 4 waves KV-split, barrier-free).
// K pre-scaled by 0.125*log2(e) -> P = exp2(st) directly. nj-streamed pipeline.
// launch_bounds (256,2): hipcc caps VGPR at ~256/w — w=2 gives the 128 VGPR
// this kernel needs; w=4 caused 64-VGPR spill storms (R6/R8).
// XCD-local KV: dispatch round-robins blockIdx across the 8 XCDs; head is
// derived from bid so that KV group g's blocks land only on XCDs {2g, 2g+1}
// -> K/V (1MB/group) stays resident in those two L2s, loads are XCD-local.
__global__ __launch_bounds__(256, 2) void attn_kernel(const bf16_t* __restrict__ qkv,
                                                      const bf16_t* __restrict__ kp,
                                                      const bf16_t* __restrict__ vt,
                                                      bf16_t* __restrict__ ctx,
                                                      float* __restrict__ Opart,
                                                      float* __restrict__ lpart) {
  int tid = threadIdx.x, lane = tid & 63, w = tid >> 6;
  int l15 = lane & 15, lhi = lane >> 4;
  int e = l15 & 7;
  int bid = blockIdx.x;
  int pos = bid & 15, qq = bid >> 4;
  int g = (pos & 7) >> 1;                        // KV group -> XCDs {2g, 2g+1}
  int h = g * 4 + (((pos >> 3) << 1) | (pos & 1));
  int p = qq >> 1, half = qq & 1;

  __shared__ alignas(16) char smem[34816 + 256];
  char* pbuf = smem + w * 8192;
  float* ilbuf = (float*)(smem + 34816);

  const bf16_t* kbase = kp + (size_t)g * 4096 * 64;
  const bf16_t* vbase = vt + (size_t)g * 64 * 4096;

  auto runPhase = [&](int tile, int sbeg, int send, bool fin,
                      float* Oslot, float* lslot) {
    int r0 = tile * 64;
    bf16x8 qf[4][2];
#pragma unroll
    for (int mi = 0; mi < 4; ++mi)
#pragma unroll
      for (int ks = 0; ks < 2; ++ks)
        qf[mi][ks] = *reinterpret_cast<const bf16x8*>(
            qkv + (size_t)(r0 + mi * 16 + l15) * 1536 + h * 64 + ks * 32 + lhi * 8);

    f32x4 O[4][4] = {};
    float lsum[4] = {0.f, 0.f, 0.f, 0.f};

    for (int step = sbeg + w; step < send; step += 4) {
      int j0 = step * 64;
      // ---- K fragments, XCD-local L2
      bf16x8 kf[4][2];
#pragma unroll
      for (int nj = 0; nj < 4; ++nj) {
        const bf16_t* kr = kbase + (size_t)(j0 + nj * 16 + l15) * 64 + lhi * 8;
        kf[nj][0] = *reinterpret_cast<const bf16x8*>(kr);
        kf[nj][1] = *reinterpret_cast<const bf16x8*>(kr + 32);
      }
      bool diag = (j0 + 64 > r0);
      // ---- streamed QKT -> exp2 -> pack -> P-LDS, one nj-group at a time
#pragma unroll
      for (int nj = 0; nj < 4; ++nj) {
        f32x4 stn[4];
#pragma unroll
        for (int mi = 0; mi < 4; ++mi) {
          f32x4 t = {0.f, 0.f, 0.f, 0.f};
          t = MFMA16(kf[nj][0], qf[mi][0], t);
          t = MFMA16(kf[nj][1], qf[mi][1], t);
          stn[mi] = t;
        }
        if (diag) {
#pragma unroll
          for (int mi = 0; mi < 4; ++mi)
#pragma unroll
            for (int r = 0; r < 4; ++r) {
              int key = j0 + nj * 16 + lhi * 4 + r;
              int qr  = r0 + mi * 16 + l15;
              if (key > qr) stn[mi][r] = -1e30f;
            }
        }
        int sw = (nj * 2 + (lhi >> 1)) ^ e;
#pragma unroll
        for (int mi = 0; mi < 4; ++mi) {
          float ls = 0.f;
          union { bf16_t hh[4]; uint64_t u; } a;
#pragma unroll
          for (int r = 0; r < 4; ++r) {
            float pv = exp2f(stn[mi][r]);
            ls += pv;
            a.hh[r] = (bf16_t)pv;
          }
          lsum[mi] += ls;
          char* prow = pbuf + (mi * 16 + l15) * 128 + ((lhi & 1) << 3);
          *reinterpret_cast<uint64_t*>(prow + sw * 16) = a.u;
        }
      }
      // ---- PV: A = P (qrow=l15), B = V^T (hd=l15)
      bf16x8 ap[4][2];
#pragma unroll
      for (int mi = 0; mi < 4; ++mi)
#pragma unroll
        for (int ks = 0; ks < 2; ++ks)
          ap[mi][ks] = *reinterpret_cast<const bf16x8*>(
              pbuf + (mi * 16 + l15) * 128 + (((ks * 4 + lhi) ^ e) << 4));
#pragma unroll
      for (int h4 = 0; h4 < 4; ++h4) {
        const bf16_t* vr = vbase + (size_t)(h4 * 16 + l15) * 4096 + j0 + lhi * 8;
        bf16x8 v0 = *reinterpret_cast<const bf16x8*>(vr);
        bf16x8 v1 = *reinterpret_cast<const bf16x8*>(vr + 32);
#pragma unroll
        for (int mi = 0; mi < 4; ++mi) {
          O[mi][h4] = MFMA16(ap[mi][0], v0, O[mi][h4]);
          O[mi][h4] = MFMA16(ap[mi][1], v1, O[mi][h4]);
        }
      }
    }

    // ---- in-block combine (regions overlay dead pbufs)
    auto WRr = [&](int r) {
      float* ob = (float*)(smem + r * 17408) + lane * 64;
#pragma unroll
      for (int mi = 0; mi < 4; ++mi)
#pragma unroll
        for (int h4 = 0; h4 < 4; ++h4)
          *reinterpret_cast<f32x4*>(ob + (((mi * 4 + h4) ^ e) << 2)) = O[mi][h4];
      f32x4 lv = {lsum[0], lsum[1], lsum[2], lsum[3]};
      *reinterpret_cast<f32x4*>(smem + r * 17408 + 16384 + lane * 16) = lv;
    };
    auto RDr = [&](int r) {
      const float* ob = (const float*)(smem + r * 17408) + lane * 64;
#pragma unroll
      for (int mi = 0; mi < 4; ++mi)
#pragma unroll
        for (int h4 = 0; h4 < 4; ++h4)
          O[mi][h4] += *reinterpret_cast<const f32x4*>(ob + (((mi * 4 + h4) ^ e) << 2));
      f32x4 lv = *reinterpret_cast<const f32x4*>(smem + r * 17408 + 16384 + lane * 16);
#pragma unroll
      for (int mi = 0; mi < 4; ++mi) lsum[mi] += lv[mi];
    };

    __syncthreads();
    if (w == 1) WRr(0);
    if (w == 2) WRr(1);
    __syncthreads();
    if (w == 0) { RDr(0); RDr(1); }
    __syncthreads();
    if (w == 3) WRr(0);
    __syncthreads();
    if (w == 0) {
      RDr(0);
#pragma unroll
      for (int mi = 0; mi < 4; ++mi) {
        float l = lsum[mi];
        l += __shfl_xor(l, 16);
        l += __shfl_xor(l, 32);
        if (fin) {
          if (lhi == 0) ilbuf[mi * 16 + l15] = 1.0f / l;
        } else {
          if (lhi == 0) lslot[mi * 16 + l15] = l;
        }
      }
      if (fin) {
#pragma unroll
        for (int mi = 0; mi < 4; ++mi) {
          f32x4 il = *reinterpret_cast<const f32x4*>(ilbuf + mi * 16 + lhi * 4);
#pragma unroll
          for (int h4 = 0; h4 < 4; ++h4)
#pragma unroll
            for (int r = 0; r < 4; ++r) O[mi][h4][r] *= il[r];
        }
      }
    }
    __syncthreads();   // w0 done with LDS; release pbuf for next phase
    if (w == 0) {
      if (fin) {
#pragma unroll
        for (int mi = 0; mi < 4; ++mi)
#pragma unroll
          for (int h4 = 0; h4 < 4; ++h4)
#pragma unroll
            for (int r = 0; r < 4; ++r) {
              int row = r0 + mi * 16 + lhi * 4 + r;
              ctx[(size_t)row * 1024 + h * 64 + h4 * 16 + l15] = (bf16_t)O[mi][h4][r];
            }
      } else {
#pragma unroll
        for (int mi = 0; mi < 4; ++mi)
#pragma unroll
          for (int h4 = 0; h4 < 4; ++h4)
            *reinterpret_cast<f32x4*>(Oslot + (mi * 4 + h4) * 256 + lane * 4) = O[mi][h4];
      }
    }
  };

  if (half == 0) {
    bool fin = (p == 31);
    int u = (30 - p) * 16 + h;
    float* Os = fin ? nullptr : Opart + ((size_t)u * 2 + 0) * 4096;
    float* ls = fin ? nullptr : lpart + ((size_t)u * 2 + 0) * 64;
    runPhase(63 - p, 0, 33, fin, Os, ls);
  } else {
    if (p < 31) {
      int u = (30 - p) * 16 + h;
      runPhase(63 - p, 33, 64 - p, false,
               Opart + ((size_t)u * 2 + 1) * 4096, lpart + ((size_t)u * 2 + 1) * 64);
    }
    runPhase(p, 0, p + 1, true, nullptr, nullptr);
  }
}

// ---------------------------------------------------------------- combine split-tile partials
__global__ __launch_bounds__(256) void norm_combine(const float* __restrict__ Opart,
                                                    const float* __restrict__ lpart,
                                                    bf16_t* __restrict__ ctx) {
  int u = blockIdx.x;
  int T = 33 + (u >> 4), h = u & 15;
  int t = threadIdx.x;
  int lane = t & 63, mi = t >> 6;
  int l15 = lane & 15, lhi = lane >> 4;
  const float* O0 = Opart + (size_t)u * 2 * 4096;
  const float* O1 = O0 + 4096;
  const float* l0 = lpart + (size_t)u * 2 * 64;
  const float* l1 = l0 + 64;
  float il[4];
#pragma unroll
  for (int r = 0; r < 4; ++r) {
    int row = mi * 16 + lhi * 4 + r;
    il[r] = 1.0f / (l0[row] + l1[row]);
  }
#pragma unroll
  for (int h4 = 0; h4 < 4; ++h4) {
    int idx = (mi * 4 + h4) * 256 + lane * 4;
    f32x4 a = *reinterpret_cast<const f32x4*>(O0 + idx);
    f32x4 b = *reinterpret_cast<const f32x4*>(O1 + idx);
#pragma unroll
    for (int r = 0; r < 4; ++r) {
      int row = mi * 16 + lhi * 4 + r;
      ctx[(size_t)(T * 64 + row) * 1024 + h * 64 + h4 * 16 + l15] =
          (bf16_t)((a[r] + b[r]) * il[r]);
    }
  }
}

// ---------------------------------------------------------------- launch
extern "C" void kernel_launch(void* const* d_in, const int* in_sizes, int n_in,
                              void* d_out, int out_size, void* d_ws, size_t ws_size,
                              hipStream_t stream) {
  const float* x  = (const float*)d_in[0];
  const float* wq = (const float*)d_in[1];
  const float* wk = (const float*)d_in[2];
  const float* wv = (const float*)d_in[3];
  const float* wo = (const float*)d_in[4];
  float* out = (float*)d_out;

  char* ws = (char*)d_ws;
  size_t off = 0;
  auto alloc = [&](size_t b) {
    char* p = ws + off;
    off += (b + 255) & ~(size_t)255;
    return p;
  };
  bf16_t* wob  = (bf16_t*)alloc((size_t)1024 * 1024 * 2);
  bf16_t* qkv  = (bf16_t*)alloc((size_t)4096 * 1536 * 2);
  bf16_t* vtb  = (bf16_t*)alloc((size_t)256 * 4096 * 2);
  bf16_t* kpb  = (bf16_t*)alloc((size_t)4 * 4096 * 64 * 2);
  bf16_t* ctx  = (bf16_t*)alloc((size_t)4096 * 1024 * 2);
  size_t scratch_base = off;
  bf16_t* xb   = (bf16_t*)alloc((size_t)4096 * 1024 * 2);
  bf16_t* wqkv = (bf16_t*)alloc((size_t)1536 * 1024 * 2);
  float* Opart = (float*)(ws + scratch_base);
  float* lpart = Opart + (size_t)496 * 2 * 4096;

  cvt_all<<<3328, 256, 0, stream>>>(x, wq, wk, wv, wo, xb, wqkv, wob);
  gemm_bt<bf16_t><<<dim3(12, 32), 256, 0, stream>>>(xb, wqkv, qkv, 4096, 1536, 1024,
                                                    kpb, vtb);
  attn_kernel<<<1024, 256, 0, stream>>>(qkv, kpb, vtb, ctx, Opart, lpart);
  norm_combine<<<496, 256, 0, stream>>>(Opart, lpart, ctx);
  gemm_bt<float><<<dim3(8, 32), 256, 0, stream>>>(ctx, wob, out, 4096, 1024, 1024,
                                                  nullptr, nullptr);
}